// Round 5
// baseline (549.445 us; speedup 1.0000x reference)
//
#include <hip/hip_runtime.h>
#include <cstddef>

// Depthwise 7x7 conv, stride 1, pad 3, 4-fold rotational kernel symmetrization.
// x: [16,384,64,64] fp32, w: [384,1,7,7] fp32, out: [16,384,64,64] fp32.
//
// R6: R5 body UNCHANGED; only the launch attribute moves.
// R5 post-mortem: structure is clean (WRITE exactly 98MB -> zero spills,
// 0 bank conflicts, FETCH 59MB) but OccupancyPercent pinned at 25.4% = 2
// waves/SIMD == the __launch_bounds__ 2nd arg. Cross-round pattern:
// arg 2 -> 25%, arg 4 -> 35%, arg 8 -> 63%: the waves-per-EU declaration
// tracks the achieved-occupancy ceiling. With 2 waves/SIMD, per-wave load
// latency (~1400cy/batch) can't hide behind one peer's FMA stream ->
// VALUBusy 34%, dur 63us vs ~21us VALU + ~26us HBM floors.
//  - (256,6): VGPR cap ~85; R5 allocator used 80 -> codegen should be
//    IDENTICAL (clean single-variable A/B), occupancy ceiling 2->6 waves/SIMD.
// Body (from R5): zero-LDS, DPP halo exchange. Thread = 4 cols x 8 out rows;
// per input row ONE aligned global_load_dwordx4 (wave = 4x 256B dense runs),
// 6 DPP movs (bound_ctrl=1 zeroes at 16-lane rows == image col edges),
// 112 FMA. Weights via readfirstlane-uniform scalar loads -> SGPRs.

#define BLOCK 256

// --- compile-time C4 orbit table for the symmetrized 7x7 kernel (13 orbits) ---
constexpr int canon_of(int k) {
    const int i = k / 7, j = k % 7;
    const int a = i * 7 + j;
    const int b = j * 7 + (6 - i);
    const int c = (6 - i) * 7 + (6 - j);
    const int d = (6 - j) * 7 + i;
    int m = a;
    if (b < m) m = b;
    if (c < m) m = c;
    if (d < m) m = d;
    return m;
}
struct Tab { int cidx[49]; };
constexpr Tab build_tab() {
    Tab t{};
    int u = 0;
    for (int k = 0; k < 49; ++k)
        if (canon_of(k) == k) { t.cidx[k] = u; ++u; }
    for (int k = 0; k < 49; ++k) t.cidx[k] = t.cidx[canon_of(k)];
    return t;
}
constexpr Tab TAB = build_tab();

// DPP lane shifts within 16-lane rows. bound_ctrl=1: invalid source lane -> 0,
// which implements the column-edge zero padding for free (lane rows of 16
// align exactly with cg = lane&15 and the 64-col image edges).
__device__ __forceinline__ float dpp_shr1(float v) {   // lane l <- lane l-1
    return __int_as_float(__builtin_amdgcn_update_dpp(
        0, __float_as_int(v), 0x111, 0xF, 0xF, true));
}
__device__ __forceinline__ float dpp_shl1(float v) {   // lane l <- lane l+1
    return __int_as_float(__builtin_amdgcn_update_dpp(
        0, __float_as_int(v), 0x101, 0xF, 0xF, true));
}

__global__ __launch_bounds__(BLOCK, 6) void dwconv7_sym_kernel(
    const float* __restrict__ x, const float* __restrict__ w,
    float* __restrict__ out, int C)
{
    const int tid = threadIdx.x;
    // 2 planes per block; p is wave-uniform (proven via readfirstlane) so the
    // weight path compiles to scalar loads into SGPRs.
    const int p = __builtin_amdgcn_readfirstlane(tid >> 7);
    const int plane = blockIdx.x * 2 + p;    // n*C + c
    const int c = plane % C;

    // --- symmetrized unique weights -> 13 scalar regs ---
    const float* __restrict__ wc = w + c * 49;
    float wu[13];
    #pragma unroll
    for (int k = 0; k < 49; ++k) {
        if (canon_of(k) == k) {
            const int i = k / 7, j = k % 7;
            wu[TAB.cidx[k]] = 0.25f * (wc[i * 7 + j]
                                     + wc[j * 7 + (6 - i)]
                                     + wc[(6 - i) * 7 + (6 - j)]
                                     + wc[(6 - j) * 7 + i]);
        }
    }

    const int idx = tid & 127;               // thread within plane
    const int cg = idx & 15;                 // col strip: cols 4cg..4cg+3
    const int S  = idx >> 4;                 // 0..7: out rows 8S..8S+7
    const int y0 = S << 3;
    const int x0 = cg << 2;
    const float* __restrict__ xp = x + (size_t)plane * 4096 + x0;
    float* __restrict__ ob = out + (size_t)plane * 4096 + y0 * 64 + x0;

    float acc[8][4];
    #pragma unroll
    for (int t = 0; t < 8; ++t)
        #pragma unroll
        for (int d = 0; d < 4; ++d) acc[t][d] = 0.f;

    // input rows y0-3 .. y0+10; row m contributes to out rows t in
    // [max(0,m-6), min(7,m)] via kernel row i = m - t. All indices static.
    #pragma unroll
    for (int m = 0; m < 14; ++m) {
        const int row = y0 - 3 + m;
        const int rr = row < 0 ? 0 : (row > 63 ? 63 : row);  // safe address
        float4 b = *(const float4*)(xp + rr * 64);
        if ((unsigned)row >= 64u) {          // top/bottom zero padding
            b.x = 0.f; b.y = 0.f; b.z = 0.f; b.w = 0.f;
        }
        // halo from neighbor lanes (zeros injected at image column edges)
        const float l1 = dpp_shr1(b.y);      // col x0-3
        const float l2 = dpp_shr1(b.z);      // col x0-2
        const float l3 = dpp_shr1(b.w);      // col x0-1
        const float h4 = dpp_shl1(b.x);      // col x0+4
        const float h5 = dpp_shl1(b.y);      // col x0+5
        const float h6 = dpp_shl1(b.z);      // col x0+6
        // r_[1..10] = cols x0-3 .. x0+6 (indices 0 and 11 never referenced)
        const float r_[12] = {0.f, l1, l2, l3, b.x, b.y, b.z, b.w,
                              h4, h5, h6, 0.f};
        #pragma unroll
        for (int t = 0; t < 8; ++t) {
            if (t <= m && m <= t + 6) {      // constant after unroll
                const int i = m - t;         // kernel row
                #pragma unroll
                for (int d = 0; d < 4; ++d)
                    #pragma unroll
                    for (int j = 0; j < 7; ++j)
                        acc[t][d] += r_[d + j + 1] * wu[TAB.cidx[i * 7 + j]];
            }
        }
    }

    // --- stores: per wave instr = 4x 256B dense aligned segments ---
    #pragma unroll
    for (int t = 0; t < 8; ++t) {
        float4 v;
        v.x = acc[t][0]; v.y = acc[t][1]; v.z = acc[t][2]; v.w = acc[t][3];
        *(float4*)(ob + t * 64) = v;
    }
}

extern "C" void kernel_launch(void* const* d_in, const int* in_sizes, int n_in,
                              void* d_out, int out_size, void* d_ws, size_t ws_size,
                              hipStream_t stream) {
    const float* x = (const float*)d_in[0];
    const float* w = (const float*)d_in[1];
    float* out = (float*)d_out;

    const int planes = in_sizes[0] / 4096;   // N*C = 6144
    const int C = in_sizes[1] / 49;          // 384

    dwconv7_sym_kernel<<<dim3(planes / 2), dim3(BLOCK), 0, stream>>>(x, w, out, C);
}

// Round 6
// 179.192 us; speedup vs baseline: 3.0662x; 3.0662x over previous
//
#include <hip/hip_runtime.h>
#include <cstddef>

// Depthwise 7x7 conv, stride 1, pad 3, 4-fold rotational kernel symmetrization.
// x: [16,384,64,64] fp32, w: [384,1,7,7] fp32, out: [16,384,64,64] fp32.
//
// R7: R5 body + EXPLICIT 14-ROW REGISTER PREFETCH (ILP, not TLP).
// Round ledger:
//  - R5 ((256,2), serial load->consume): 63us, VGPR 80, WRITE exactly 98MB,
//    VALUBusy 34% -- one ~450cy load stall exposed per 224cy compute step.
//  - R6 ((256,6), same body): allocator shrank to 40 VGPR and spilled 700MB.
//    Lesson: waves-per-EU bound is a hard shrink-to budget on this allocator,
//    non-monotonic; (256,2) is the only proven-sane config for this body.
//  - R3 lesson inverted: mass load hoisting is only fatal under a tight cap.
//    Under (256,2)'s 256-VGPR budget, 14 rows in flight (56 VGPR) + 32 acc
//    + temps ~= 130 VGPR -- no spill possible.
// Structure: phase 1 issues all 14 global_load_dwordx4 back-to-back into a
// fully-unrolled rows[14] register array (vmcnt queue depth 14); phase 2
// consumes in order -- row m's FMAs start m*224cy after its load issued, so
// only the FIRST load's latency is ever exposed (~15% of wave work).
// DPP halo exchange unchanged: 6 movs/row, bound_ctrl=1 zeroes at 16-lane
// row boundaries == image column edges. No LDS, no barriers, no fences.

#define BLOCK 256

// --- compile-time C4 orbit table for the symmetrized 7x7 kernel (13 orbits) ---
constexpr int canon_of(int k) {
    const int i = k / 7, j = k % 7;
    const int a = i * 7 + j;
    const int b = j * 7 + (6 - i);
    const int c = (6 - i) * 7 + (6 - j);
    const int d = (6 - j) * 7 + i;
    int m = a;
    if (b < m) m = b;
    if (c < m) m = c;
    if (d < m) m = d;
    return m;
}
struct Tab { int cidx[49]; };
constexpr Tab build_tab() {
    Tab t{};
    int u = 0;
    for (int k = 0; k < 49; ++k)
        if (canon_of(k) == k) { t.cidx[k] = u; ++u; }
    for (int k = 0; k < 49; ++k) t.cidx[k] = t.cidx[canon_of(k)];
    return t;
}
constexpr Tab TAB = build_tab();

// DPP lane shifts within 16-lane rows. bound_ctrl=1: invalid source lane -> 0,
// implementing the column-edge zero padding for free (16-lane rows align
// exactly with cg = lane&15 and the 64-col image edges).
__device__ __forceinline__ float dpp_shr1(float v) {   // lane l <- lane l-1
    return __int_as_float(__builtin_amdgcn_update_dpp(
        0, __float_as_int(v), 0x111, 0xF, 0xF, true));
}
__device__ __forceinline__ float dpp_shl1(float v) {   // lane l <- lane l+1
    return __int_as_float(__builtin_amdgcn_update_dpp(
        0, __float_as_int(v), 0x101, 0xF, 0xF, true));
}

__global__ __launch_bounds__(BLOCK, 2) void dwconv7_sym_kernel(
    const float* __restrict__ x, const float* __restrict__ w,
    float* __restrict__ out, int C)
{
    const int tid = threadIdx.x;
    // 2 planes per block; p is wave-uniform (proven via readfirstlane) so the
    // weight path compiles to scalar loads into SGPRs.
    const int p = __builtin_amdgcn_readfirstlane(tid >> 7);
    const int plane = blockIdx.x * 2 + p;    // n*C + c
    const int c = plane % C;

    const int idx = tid & 127;               // thread within plane
    const int cg = idx & 15;                 // col strip: cols 4cg..4cg+3
    const int S  = idx >> 4;                 // 0..7: out rows 8S..8S+7
    const int y0 = S << 3;
    const int x0 = cg << 2;
    const float* __restrict__ xp = x + (size_t)plane * 4096 + x0;
    float* __restrict__ ob = out + (size_t)plane * 4096 + y0 * 64 + x0;

    // --- phase 1: issue ALL 14 row loads back-to-back (registers, unrolled).
    //     Addresses are clamped; OOB rows get zeroed at consume time. ---
    float4 rows[14];
    #pragma unroll
    for (int m = 0; m < 14; ++m) {
        const int row = y0 - 3 + m;
        const int rr = row < 0 ? 0 : (row > 63 ? 63 : row);
        rows[m] = *(const float4*)(xp + rr * 64);
    }

    // --- symmetrized unique weights -> 13 scalar regs (s_loads overlap the
    //     vmem latency of phase 1) ---
    const float* __restrict__ wc = w + c * 49;
    float wu[13];
    #pragma unroll
    for (int k = 0; k < 49; ++k) {
        if (canon_of(k) == k) {
            const int i = k / 7, j = k % 7;
            wu[TAB.cidx[k]] = 0.25f * (wc[i * 7 + j]
                                     + wc[j * 7 + (6 - i)]
                                     + wc[(6 - i) * 7 + (6 - j)]
                                     + wc[(6 - j) * 7 + i]);
        }
    }

    float acc[8][4];
    #pragma unroll
    for (int t = 0; t < 8; ++t)
        #pragma unroll
        for (int d = 0; d < 4; ++d) acc[t][d] = 0.f;

    // --- phase 2: consume rows in order; row m contributes to out rows t in
    //     [max(0,m-6), min(7,m)] via kernel row i = m - t. All static. ---
    #pragma unroll
    for (int m = 0; m < 14; ++m) {
        const int row = y0 - 3 + m;
        float4 b = rows[m];
        if ((unsigned)row >= 64u) {          // top/bottom zero padding
            b.x = 0.f; b.y = 0.f; b.z = 0.f; b.w = 0.f;
        }
        // halo from neighbor lanes (zeros injected at image column edges)
        const float l1 = dpp_shr1(b.y);      // col x0-3
        const float l2 = dpp_shr1(b.z);      // col x0-2
        const float l3 = dpp_shr1(b.w);      // col x0-1
        const float h4 = dpp_shl1(b.x);      // col x0+4
        const float h5 = dpp_shl1(b.y);      // col x0+5
        const float h6 = dpp_shl1(b.z);      // col x0+6
        // r_[1..10] = cols x0-3 .. x0+6 (indices 0 and 11 never referenced)
        const float r_[12] = {0.f, l1, l2, l3, b.x, b.y, b.z, b.w,
                              h4, h5, h6, 0.f};
        #pragma unroll
        for (int t = 0; t < 8; ++t) {
            if (t <= m && m <= t + 6) {      // constant after unroll
                const int i = m - t;         // kernel row
                #pragma unroll
                for (int d = 0; d < 4; ++d)
                    #pragma unroll
                    for (int j = 0; j < 7; ++j)
                        acc[t][d] += r_[d + j + 1] * wu[TAB.cidx[i * 7 + j]];
            }
        }
    }

    // --- stores: per wave instr = 4x 256B dense aligned segments ---
    #pragma unroll
    for (int t = 0; t < 8; ++t) {
        float4 v;
        v.x = acc[t][0]; v.y = acc[t][1]; v.z = acc[t][2]; v.w = acc[t][3];
        *(float4*)(ob + t * 64) = v;
    }
}

extern "C" void kernel_launch(void* const* d_in, const int* in_sizes, int n_in,
                              void* d_out, int out_size, void* d_ws, size_t ws_size,
                              hipStream_t stream) {
    const float* x = (const float*)d_in[0];
    const float* w = (const float*)d_in[1];
    float* out = (float*)d_out;

    const int planes = in_sizes[0] / 4096;   // N*C = 6144
    const int C = in_sizes[1] / 49;          // 384

    dwconv7_sym_kernel<<<dim3(planes / 2), dim3(BLOCK), 0, stream>>>(x, w, out, C);
}

// Round 7
// 178.995 us; speedup vs baseline: 3.0696x; 1.0011x over previous
//
#include <hip/hip_runtime.h>
#include <cstddef>

// Depthwise 7x7 conv, stride 1, pad 3, 4-fold rotational kernel symmetrization.
// x: [16,384,64,64] fp32, w: [384,1,7,7] fp32, out: [16,384,64,64] fp32.
//
// R8: R7 body byte-identical; ONLY the launch attribute changes:
//     __launch_bounds__(256,2)  ->  __launch_bounds__(256)   (one-arg form)
// Why: cross-round evidence that hipcc emits the 2nd arg as
// amdgpu-waves-per-eu={N,N} -- BOTH an allocator floor (R6: declared 6,
// allocator squeezed 104->40 VGPR, 700MB scratch spills) AND a residency CAP
// (R5: VGPR 80, HW could host 6 waves/SIMD, measured exactly 2 = declared;
// R7: VGPR 104, HW could host 4, measured <=2 = declared). The 63us plateau
// across 5 structures is exposed per-row load latency (~900cy vs 392cy FMA
// per row -> VALUBusy 32% matches) with only 2 waves/SIMD to hide it.
// One-arg form sets flat-work-group-size=256 only, no waves-per-eu: allocator
// keeps its natural 104 VGPR (proven un-squeezed in R7), residency floats to
// 512/104 = 4 waves/SIMD.
// Body (R7): zero-LDS, DPP halo exchange, 14-row register prefetch.
//  - phase 1: all 14 global_load_dwordx4 issued back-to-back into rows[14]
//    (vmcnt depth 14; only first load's latency exposed within a wave).
//  - phase 2: consume in order; 6 DPP movs/row (bound_ctrl=1 zeroes at
//    16-lane row boundaries == image column edges), 112 FMA/row.
//  - weights: readfirstlane-uniform scalar loads -> SGPRs.
//  - stores: 4x 256B dense aligned segments per wave instruction.

#define BLOCK 256

// --- compile-time C4 orbit table for the symmetrized 7x7 kernel (13 orbits) ---
constexpr int canon_of(int k) {
    const int i = k / 7, j = k % 7;
    const int a = i * 7 + j;
    const int b = j * 7 + (6 - i);
    const int c = (6 - i) * 7 + (6 - j);
    const int d = (6 - j) * 7 + i;
    int m = a;
    if (b < m) m = b;
    if (c < m) m = c;
    if (d < m) m = d;
    return m;
}
struct Tab { int cidx[49]; };
constexpr Tab build_tab() {
    Tab t{};
    int u = 0;
    for (int k = 0; k < 49; ++k)
        if (canon_of(k) == k) { t.cidx[k] = u; ++u; }
    for (int k = 0; k < 49; ++k) t.cidx[k] = t.cidx[canon_of(k)];
    return t;
}
constexpr Tab TAB = build_tab();

// DPP lane shifts within 16-lane rows. bound_ctrl=1: invalid source lane -> 0,
// implementing the column-edge zero padding for free (16-lane rows align
// exactly with cg = lane&15 and the 64-col image edges).
__device__ __forceinline__ float dpp_shr1(float v) {   // lane l <- lane l-1
    return __int_as_float(__builtin_amdgcn_update_dpp(
        0, __float_as_int(v), 0x111, 0xF, 0xF, true));
}
__device__ __forceinline__ float dpp_shl1(float v) {   // lane l <- lane l+1
    return __int_as_float(__builtin_amdgcn_update_dpp(
        0, __float_as_int(v), 0x101, 0xF, 0xF, true));
}

__global__ __launch_bounds__(BLOCK) void dwconv7_sym_kernel(
    const float* __restrict__ x, const float* __restrict__ w,
    float* __restrict__ out, int C)
{
    const int tid = threadIdx.x;
    // 2 planes per block; p is wave-uniform (proven via readfirstlane) so the
    // weight path compiles to scalar loads into SGPRs.
    const int p = __builtin_amdgcn_readfirstlane(tid >> 7);
    const int plane = blockIdx.x * 2 + p;    // n*C + c
    const int c = plane % C;

    const int idx = tid & 127;               // thread within plane
    const int cg = idx & 15;                 // col strip: cols 4cg..4cg+3
    const int S  = idx >> 4;                 // 0..7: out rows 8S..8S+7
    const int y0 = S << 3;
    const int x0 = cg << 2;
    const float* __restrict__ xp = x + (size_t)plane * 4096 + x0;
    float* __restrict__ ob = out + (size_t)plane * 4096 + y0 * 64 + x0;

    // --- phase 1: issue ALL 14 row loads back-to-back (registers, unrolled).
    //     Addresses are clamped; OOB rows get zeroed at consume time. ---
    float4 rows[14];
    #pragma unroll
    for (int m = 0; m < 14; ++m) {
        const int row = y0 - 3 + m;
        const int rr = row < 0 ? 0 : (row > 63 ? 63 : row);
        rows[m] = *(const float4*)(xp + rr * 64);
    }

    // --- symmetrized unique weights -> 13 scalar regs (s_loads overlap the
    //     vmem latency of phase 1) ---
    const float* __restrict__ wc = w + c * 49;
    float wu[13];
    #pragma unroll
    for (int k = 0; k < 49; ++k) {
        if (canon_of(k) == k) {
            const int i = k / 7, j = k % 7;
            wu[TAB.cidx[k]] = 0.25f * (wc[i * 7 + j]
                                     + wc[j * 7 + (6 - i)]
                                     + wc[(6 - i) * 7 + (6 - j)]
                                     + wc[(6 - j) * 7 + i]);
        }
    }

    float acc[8][4];
    #pragma unroll
    for (int t = 0; t < 8; ++t)
        #pragma unroll
        for (int d = 0; d < 4; ++d) acc[t][d] = 0.f;

    // --- phase 2: consume rows in order; row m contributes to out rows t in
    //     [max(0,m-6), min(7,m)] via kernel row i = m - t. All static. ---
    #pragma unroll
    for (int m = 0; m < 14; ++m) {
        const int row = y0 - 3 + m;
        float4 b = rows[m];
        if ((unsigned)row >= 64u) {          // top/bottom zero padding
            b.x = 0.f; b.y = 0.f; b.z = 0.f; b.w = 0.f;
        }
        // halo from neighbor lanes (zeros injected at image column edges)
        const float l1 = dpp_shr1(b.y);      // col x0-3
        const float l2 = dpp_shr1(b.z);      // col x0-2
        const float l3 = dpp_shr1(b.w);      // col x0-1
        const float h4 = dpp_shl1(b.x);      // col x0+4
        const float h5 = dpp_shl1(b.y);      // col x0+5
        const float h6 = dpp_shl1(b.z);      // col x0+6
        // r_[1..10] = cols x0-3 .. x0+6 (indices 0 and 11 never referenced)
        const float r_[12] = {0.f, l1, l2, l3, b.x, b.y, b.z, b.w,
                              h4, h5, h6, 0.f};
        #pragma unroll
        for (int t = 0; t < 8; ++t) {
            if (t <= m && m <= t + 6) {      // constant after unroll
                const int i = m - t;         // kernel row
                #pragma unroll
                for (int d = 0; d < 4; ++d)
                    #pragma unroll
                    for (int j = 0; j < 7; ++j)
                        acc[t][d] += r_[d + j + 1] * wu[TAB.cidx[i * 7 + j]];
            }
        }
    }

    // --- stores: per wave instr = 4x 256B dense aligned segments ---
    #pragma unroll
    for (int t = 0; t < 8; ++t) {
        float4 v;
        v.x = acc[t][0]; v.y = acc[t][1]; v.z = acc[t][2]; v.w = acc[t][3];
        *(float4*)(ob + t * 64) = v;
    }
}

extern "C" void kernel_launch(void* const* d_in, const int* in_sizes, int n_in,
                              void* d_out, int out_size, void* d_ws, size_t ws_size,
                              hipStream_t stream) {
    const float* x = (const float*)d_in[0];
    const float* w = (const float*)d_in[1];
    float* out = (float*)d_out;

    const int planes = in_sizes[0] / 4096;   // N*C = 6144
    const int C = in_sizes[1] / 49;          // 384

    dwconv7_sym_kernel<<<dim3(planes / 2), dim3(BLOCK), 0, stream>>>(x, w, out, C);
}